// Round 1
// baseline (3125.458 us; speedup 1.0000x reference)
//
#include <hip/hip_runtime.h>
#include <hip/hip_bf16.h>
#include <math.h>

#define HIDDEN 4096
#define HID2   8192
#define ODIM   1792
#define NB     4096   // batch

typedef unsigned short u16;
typedef __attribute__((ext_vector_type(8))) short bf16x8;
typedef __attribute__((ext_vector_type(4))) float f32x4;

__device__ __forceinline__ u16 bf16r(float f) {
  union { float f; unsigned u; } a; a.f = f;
  unsigned r = a.u + 0x7fffu + ((a.u >> 16) & 1u);
  return (u16)(r >> 16);
}

#define GLDS16(g, l) __builtin_amdgcn_global_load_lds(                          \
    (const __attribute__((address_space(1))) void*)(g),                         \
    (__attribute__((address_space(3))) void*)(l), 16, 0, 0)

// ---------------- fp32 -> bf16 (no transpose), float4 per thread ----------
__global__ void convx_k(const float* __restrict__ x, u16* __restrict__ xb, int n4) {
  int i = blockIdx.x * blockDim.x + threadIdx.x;
  if (i >= n4) return;
  float4 v = ((const float4*)x)[i];
  ushort4 o;
  o.x = bf16r(v.x); o.y = bf16r(v.y); o.z = bf16r(v.z); o.w = bf16r(v.w);
  ((ushort4*)xb)[i] = o;
}

// ------------- fp32 [K][N] -> bf16 [N][K] transpose-convert, 64x64 tiles ---
__global__ void convT_k(const float* __restrict__ W, u16* __restrict__ WT,
                        int K, int N) {
  __shared__ u16 t[64 * 65];
  const int n0 = blockIdx.x * 64, k0 = blockIdx.y * 64;
  const int c = (threadIdx.x & 15) * 4;  // 4-wide column group
  const int r = threadIdx.x >> 4;        // 16 rows/pass
#pragma unroll
  for (int p = 0; p < 4; ++p) {
    int k = r + p * 16;
    float4 v = *(const float4*)&W[(size_t)(k0 + k) * N + n0 + c];
    t[(c + 0) * 65 + k] = bf16r(v.x);
    t[(c + 1) * 65 + k] = bf16r(v.y);
    t[(c + 2) * 65 + k] = bf16r(v.z);
    t[(c + 3) * 65 + k] = bf16r(v.w);
  }
  __syncthreads();
#pragma unroll
  for (int p = 0; p < 4; ++p) {
    int n = r + p * 16;
    ushort4 o;
    o.x = t[n * 65 + c + 0]; o.y = t[n * 65 + c + 1];
    o.z = t[n * 65 + c + 2]; o.w = t[n * 65 + c + 3];
    *(ushort4*)&WT[(size_t)(n0 + n) * K + k0 + c] = o;
  }
}

// ---------------- router: logits -> top-2 -> renorm gate [NB][4] -----------
__global__ void router_k(const float* __restrict__ x, const float* __restrict__ rw,
                         const float* __restrict__ rb, float* __restrict__ gate) {
  const int t = blockIdx.x;
  float p0 = 0, p1 = 0, p2 = 0, p3 = 0;
  const float* xr = x + (size_t)t * HIDDEN;
  for (int i = threadIdx.x; i < HIDDEN; i += 256) {
    float xv = xr[i];
    float4 w = *(const float4*)&rw[i * 4];
    p0 += xv * w.x; p1 += xv * w.y; p2 += xv * w.z; p3 += xv * w.w;
  }
  __shared__ float red[4][256];
  red[0][threadIdx.x] = p0; red[1][threadIdx.x] = p1;
  red[2][threadIdx.x] = p2; red[3][threadIdx.x] = p3;
  __syncthreads();
  for (int s = 128; s > 0; s >>= 1) {
    if (threadIdx.x < s)
      for (int e = 0; e < 4; ++e) red[e][threadIdx.x] += red[e][threadIdx.x + s];
    __syncthreads();
  }
  if (threadIdx.x == 0) {
    float l[4];
    for (int e = 0; e < 4; ++e) l[e] = red[e][0] + rb[e];
    int a = 0;
    for (int e = 1; e < 4; ++e) if (l[e] > l[a]) a = e;
    int b = -1;
    for (int e = 0; e < 4; ++e) {
      if (e == a) continue;
      if (b < 0 || l[e] > l[b]) b = e;
    }
    float ga = 1.0f / (1.0f + expf(l[b] - l[a]));
    float g[4] = {0.f, 0.f, 0.f, 0.f};
    g[a] = ga; g[b] = 1.0f - ga;
    for (int e = 0; e < 4; ++e) gate[t * 4 + e] = g[e];
  }
}

// ---------------- GEMM core: 128x128 tile, BK=64, 4 waves of 64x64 --------
#define BM 128
#define BN 128
#define BK 64

// GEMM1: H = gelu(Xb @ W1e + b1e), A[NB][4096] bf16, Bt[8192][4096] bf16
__global__ __launch_bounds__(256, 2) void gemm1_k(
    const u16* __restrict__ A, const u16* __restrict__ Bt,
    const float* __restrict__ bias, u16* __restrict__ H) {
  __shared__ __align__(16) u16 As[BM * BK];
  __shared__ __align__(16) u16 Bs[BN * BK];
  const int K = 4096;
  const int tid = threadIdx.x;
  const int m0 = blockIdx.y * BM, n0 = blockIdx.x * BN;
  const int wave = tid >> 6, lane = tid & 63;
  const int wm = (wave >> 1) * 64, wn = (wave & 1) * 64;
  const int lrow = lane & 15, lko = (lane >> 4) * 8;
  const int srow = tid >> 3, scol = (tid & 7) * 8;
  f32x4 acc[4][4] = {};

  for (int kt = 0; kt < K; kt += BK) {
#pragma unroll
    for (int p = 0; p < 4; ++p) {
      int r = p * 32 + srow;
      GLDS16(A  + (size_t)(m0 + r) * K + kt + scol, As + r * BK + scol);
      GLDS16(Bt + (size_t)(n0 + r) * K + kt + scol, Bs + r * BK + scol);
    }
    __syncthreads();
#pragma unroll
    for (int kk = 0; kk < BK; kk += 32) {
      bf16x8 af[4], bfr[4];
#pragma unroll
      for (int i = 0; i < 4; ++i)
        af[i] = *(const bf16x8*)&As[(wm + i * 16 + lrow) * BK + kk + lko];
#pragma unroll
      for (int j = 0; j < 4; ++j)
        bfr[j] = *(const bf16x8*)&Bs[(wn + j * 16 + lrow) * BK + kk + lko];
#pragma unroll
      for (int i = 0; i < 4; ++i)
#pragma unroll
        for (int j = 0; j < 4; ++j)
          acc[i][j] = __builtin_amdgcn_mfma_f32_16x16x32_bf16(af[i], bfr[j], acc[i][j], 0, 0, 0);
    }
    __syncthreads();
  }
  const int crow = (lane >> 4) * 4, ccol = lane & 15;
#pragma unroll
  for (int i = 0; i < 4; ++i)
#pragma unroll
    for (int j = 0; j < 4; ++j) {
      int gr = m0 + wm + i * 16 + crow;
      int gc = n0 + wn + j * 16 + ccol;
      float b = bias[gc];
#pragma unroll
      for (int rg = 0; rg < 4; ++rg) {
        float v = acc[i][j][rg] + b;
        v = 0.5f * v * (1.0f + erff(v * 0.70710678118654752f));
        H[(size_t)(gr + rg) * HID2 + gc] = bf16r(v);
      }
    }
}

// GEMM2: out (=/+=) gate[:,e] * (H @ W2e + b2e), K=8192, N=1792
__global__ __launch_bounds__(256, 2) void gemm2_k(
    const u16* __restrict__ A, const u16* __restrict__ Bt,
    const float* __restrict__ bias, const float* __restrict__ gate,
    float* __restrict__ out, int expert) {
  __shared__ __align__(16) u16 As[BM * BK];
  __shared__ __align__(16) u16 Bs[BN * BK];
  const int K = 8192;
  const int tid = threadIdx.x;
  const int m0 = blockIdx.y * BM, n0 = blockIdx.x * BN;
  const int wave = tid >> 6, lane = tid & 63;
  const int wm = (wave >> 1) * 64, wn = (wave & 1) * 64;
  const int lrow = lane & 15, lko = (lane >> 4) * 8;
  const int srow = tid >> 3, scol = (tid & 7) * 8;
  f32x4 acc[4][4] = {};

  for (int kt = 0; kt < K; kt += BK) {
#pragma unroll
    for (int p = 0; p < 4; ++p) {
      int r = p * 32 + srow;
      GLDS16(A  + (size_t)(m0 + r) * K + kt + scol, As + r * BK + scol);
      GLDS16(Bt + (size_t)(n0 + r) * K + kt + scol, Bs + r * BK + scol);
    }
    __syncthreads();
#pragma unroll
    for (int kk = 0; kk < BK; kk += 32) {
      bf16x8 af[4], bfr[4];
#pragma unroll
      for (int i = 0; i < 4; ++i)
        af[i] = *(const bf16x8*)&As[(wm + i * 16 + lrow) * BK + kk + lko];
#pragma unroll
      for (int j = 0; j < 4; ++j)
        bfr[j] = *(const bf16x8*)&Bs[(wn + j * 16 + lrow) * BK + kk + lko];
#pragma unroll
      for (int i = 0; i < 4; ++i)
#pragma unroll
        for (int j = 0; j < 4; ++j)
          acc[i][j] = __builtin_amdgcn_mfma_f32_16x16x32_bf16(af[i], bfr[j], acc[i][j], 0, 0, 0);
    }
    __syncthreads();
  }
  const int crow = (lane >> 4) * 4, ccol = lane & 15;
#pragma unroll
  for (int i = 0; i < 4; ++i)
#pragma unroll
    for (int j = 0; j < 4; ++j) {
      int gr = m0 + wm + i * 16 + crow;
      int gc = n0 + wn + j * 16 + ccol;
      float b = bias[gc];
#pragma unroll
      for (int rg = 0; rg < 4; ++rg) {
        int r = gr + rg;
        float g = gate[r * 4 + expert];
        float v = g * (acc[i][j][rg] + b);
        size_t o = (size_t)r * ODIM + gc;
        if (expert == 0) out[o] = v; else out[o] += v;
      }
    }
}

extern "C" void kernel_launch(void* const* d_in, const int* in_sizes, int n_in,
                              void* d_out, int out_size, void* d_ws, size_t ws_size,
                              hipStream_t stream) {
  const float* X  = (const float*)d_in[0];
  const float* rw = (const float*)d_in[1];
  const float* rb = (const float*)d_in[2];
  const float* w1 = (const float*)d_in[3];
  const float* b1 = (const float*)d_in[4];
  const float* w2 = (const float*)d_in[5];
  const float* b2 = (const float*)d_in[6];
  float* out = (float*)d_out;

  // workspace layout (bytes)
  const size_t OFF_XB  = 0;                       // 4096*4096*2   = 33,554,432
  const size_t OFF_W1T = 33554432;                // 8192*4096*2   = 67,108,864
  const size_t OFF_W2T = 100663296;               // 1792*8192*2   = 29,360,128
  const size_t OFF_H   = 130023424;               // 4096*8192*2   = 67,108,864
  const size_t OFF_G   = 197132288;               // 4096*4*4      = 65,536
  const size_t NEED    = 197197824;
  if (ws_size < NEED) return;  // workspace too small: bail (output stays poisoned)

  char* ws = (char*)d_ws;
  u16*  Xb   = (u16*)(ws + OFF_XB);
  u16*  w1bT = (u16*)(ws + OFF_W1T);
  u16*  w2bT = (u16*)(ws + OFF_W2T);
  u16*  Hb   = (u16*)(ws + OFF_H);
  float* gate = (float*)(ws + OFF_G);

  convx_k<<<16384, 256, 0, stream>>>(X, Xb, 4194304);
  router_k<<<4096, 256, 0, stream>>>(X, rw, rb, gate);

  for (int e = 0; e < 4; ++e) {
    convT_k<<<dim3(HID2 / 64, HIDDEN / 64), 256, 0, stream>>>(
        w1 + (size_t)e * HIDDEN * HID2, w1bT, HIDDEN, HID2);
    gemm1_k<<<dim3(HID2 / BN, NB / BM), 256, 0, stream>>>(
        Xb, w1bT, b1 + (size_t)e * HID2, Hb);
    convT_k<<<dim3(ODIM / 64, HID2 / 64), 256, 0, stream>>>(
        w2 + (size_t)e * HID2 * ODIM, w2bT, HID2, ODIM);
    gemm2_k<<<dim3(ODIM / BN, NB / BM), 256, 0, stream>>>(
        Hb, w2bT, b2 + (size_t)e * ODIM, gate, out, e);
  }
}

// Round 2
// 2250.132 us; speedup vs baseline: 1.3890x; 1.3890x over previous
//
#include <hip/hip_runtime.h>
#include <hip/hip_bf16.h>
#include <math.h>

#define HIDDEN 4096
#define HID2   8192
#define ODIM   1792
#define NB     4096   // batch
#define CAP    4096   // per-expert row capacity (worst case)

typedef unsigned short u16;
typedef unsigned int u32;
typedef __attribute__((ext_vector_type(8))) short bf16x8;
typedef __attribute__((ext_vector_type(4))) float f32x4;

// perm entry flags
#define F_FIRST 0x80000000u   // this expert is the token's first writer ('=')
#define F_PAD   0x40000000u   // padding row: skip output store

__device__ __forceinline__ u16 bf16r(float f) {
  union { float f; unsigned u; } a; a.f = f;
  unsigned r = a.u + 0x7fffu + ((a.u >> 16) & 1u);
  return (u16)(r >> 16);
}

#define GLDS16(g, l) __builtin_amdgcn_global_load_lds(                          \
    (const __attribute__((address_space(1))) void*)(g),                         \
    (__attribute__((address_space(3))) void*)(l), 16, 0, 0)

// ---------------- fp32 -> bf16 (no transpose), float4 per thread ----------
__global__ void convx_k(const float* __restrict__ x, u16* __restrict__ xb, int n4) {
  int i = blockIdx.x * blockDim.x + threadIdx.x;
  if (i >= n4) return;
  float4 v = ((const float4*)x)[i];
  ushort4 o;
  o.x = bf16r(v.x); o.y = bf16r(v.y); o.z = bf16r(v.z); o.w = bf16r(v.w);
  ((ushort4*)xb)[i] = o;
}

// ------------- fp32 [K][N] -> bf16 [N][K] transpose-convert, 64x64 tiles ---
__global__ void convT_k(const float* __restrict__ W, u16* __restrict__ WT,
                        int K, int N) {
  __shared__ u16 t[64 * 65];
  const int n0 = blockIdx.x * 64, k0 = blockIdx.y * 64;
  const int c = (threadIdx.x & 15) * 4;
  const int r = threadIdx.x >> 4;
#pragma unroll
  for (int p = 0; p < 4; ++p) {
    int k = r + p * 16;
    float4 v = *(const float4*)&W[(size_t)(k0 + k) * N + n0 + c];
    t[(c + 0) * 65 + k] = bf16r(v.x);
    t[(c + 1) * 65 + k] = bf16r(v.y);
    t[(c + 2) * 65 + k] = bf16r(v.z);
    t[(c + 3) * 65 + k] = bf16r(v.w);
  }
  __syncthreads();
#pragma unroll
  for (int p = 0; p < 4; ++p) {
    int n = r + p * 16;
    ushort4 o;
    o.x = t[n * 65 + c + 0]; o.y = t[n * 65 + c + 1];
    o.z = t[n * 65 + c + 2]; o.w = t[n * 65 + c + 3];
    *(ushort4*)&WT[(size_t)(n0 + n) * K + k0 + c] = o;
  }
}

// ---------------- router: logits -> top-2 -> gate [NB][4] + pair ----------
__global__ void router_k(const float* __restrict__ x, const float* __restrict__ rw,
                         const float* __restrict__ rb, float* __restrict__ gate,
                         u32* __restrict__ pair) {
  const int t = blockIdx.x;
  float p0 = 0, p1 = 0, p2 = 0, p3 = 0;
  const float* xr = x + (size_t)t * HIDDEN;
  for (int i = threadIdx.x; i < HIDDEN; i += 256) {
    float xv = xr[i];
    float4 w = *(const float4*)&rw[i * 4];
    p0 += xv * w.x; p1 += xv * w.y; p2 += xv * w.z; p3 += xv * w.w;
  }
  __shared__ float red[4][256];
  red[0][threadIdx.x] = p0; red[1][threadIdx.x] = p1;
  red[2][threadIdx.x] = p2; red[3][threadIdx.x] = p3;
  __syncthreads();
  for (int s = 128; s > 0; s >>= 1) {
    if (threadIdx.x < s)
      for (int e = 0; e < 4; ++e) red[e][threadIdx.x] += red[e][threadIdx.x + s];
    __syncthreads();
  }
  if (threadIdx.x == 0) {
    float l[4];
    for (int e = 0; e < 4; ++e) l[e] = red[e][0] + rb[e];
    int a = 0;
    for (int e = 1; e < 4; ++e) if (l[e] > l[a]) a = e;
    int b = -1;
    for (int e = 0; e < 4; ++e) {
      if (e == a) continue;
      if (b < 0 || l[e] > l[b]) b = e;
    }
    float ga = 1.0f / (1.0f + expf(l[b] - l[a]));
    float g[4] = {0.f, 0.f, 0.f, 0.f};
    g[a] = ga; g[b] = 1.0f - ga;
    for (int e = 0; e < 4; ++e) gate[t * 4 + e] = g[e];
    pair[t] = (u32)a | ((u32)b << 8);
  }
}

__global__ void zero_k(int* cnt) {
  if (threadIdx.x < 4) cnt[threadIdx.x] = 0;
}

// build per-expert compact token lists
__global__ void build_k(const u32* __restrict__ pair, int* __restrict__ cnt,
                        u32* __restrict__ perm) {
  int t = blockIdx.x * 256 + threadIdx.x;
  if (t >= NB) return;
  u32 p = pair[t];
  int a = p & 0xFF, b = (p >> 8) & 0xFF;
  int pa = atomicAdd(&cnt[a], 1);
  perm[a * CAP + pa] = (u32)t | (a < b ? F_FIRST : 0u);
  int pb = atomicAdd(&cnt[b], 1);
  perm[b * CAP + pb] = (u32)t | (b < a ? F_FIRST : 0u);
}

// pad each list to a multiple of BM with skip-marked token-0 rows
__global__ void pad_k(const int* __restrict__ cnt, int* __restrict__ cntpad,
                      u32* __restrict__ perm) {
  int e = blockIdx.x;
  int c = cnt[e];
  int cp = (c + 127) & ~127;
  if (threadIdx.x == 0) cntpad[e] = cp;
  for (int i = c + threadIdx.x; i < cp; i += 128) perm[e * CAP + i] = F_PAD;
}

// ---------------- GEMM core: 128x128 tile, BK=64, 4 waves of 64x64 --------
#define BM 128
#define BN 128
#define BK 64

// GEMM1: H[pos] = gelu(X[tok[pos]] @ W1e + b1e); gathered A rows.
__global__ __launch_bounds__(256, 2) void gemm1_k(
    const u16* __restrict__ A, const u16* __restrict__ Bt,
    const float* __restrict__ bias, u16* __restrict__ H,
    const u32* __restrict__ perm, const int* __restrict__ cntpad) {
  const int m0 = blockIdx.y * BM;
  if (m0 >= *cntpad) return;
  __shared__ __align__(16) u16 As[BM * BK];
  __shared__ __align__(16) u16 Bs[BN * BK];
  const int K = HIDDEN;
  const int tid = threadIdx.x;
  const int n0 = blockIdx.x * BN;
  const int wave = tid >> 6, lane = tid & 63;
  const int wm = (wave >> 1) * 64, wn = (wave & 1) * 64;
  const int lrow = lane & 15, lko = (lane >> 4) * 8;
  const int srow = tid >> 3, scol = (tid & 7) * 8;
  const int sw = (lrow & 7) * 8;  // read-side xor swizzle (16B groups)
  f32x4 acc[4][4] = {};

  size_t arow[4];
  int ssc[4];
#pragma unroll
  for (int p = 0; p < 4; ++p) {
    int r = p * 32 + srow;
    u32 ent = perm[m0 + r];
    arow[p] = (size_t)(ent & 0xFFFFu) * K;
    ssc[p] = scol ^ ((r & 7) * 8);  // store-side swizzle: fetch permuted col
  }

  for (int kt = 0; kt < K; kt += BK) {
#pragma unroll
    for (int p = 0; p < 4; ++p) {
      int r = p * 32 + srow;
      GLDS16(A + arow[p] + kt + ssc[p], As + r * BK + scol);
      GLDS16(Bt + (size_t)(n0 + r) * K + kt + ssc[p], Bs + r * BK + scol);
    }
    __syncthreads();
#pragma unroll
    for (int kk = 0; kk < BK; kk += 32) {
      const int cx = (kk + lko) ^ sw;
      bf16x8 af[4], bfr[4];
#pragma unroll
      for (int i = 0; i < 4; ++i)
        af[i] = *(const bf16x8*)&As[(wm + i * 16 + lrow) * BK + cx];
#pragma unroll
      for (int j = 0; j < 4; ++j)
        bfr[j] = *(const bf16x8*)&Bs[(wn + j * 16 + lrow) * BK + cx];
#pragma unroll
      for (int i = 0; i < 4; ++i)
#pragma unroll
        for (int j = 0; j < 4; ++j)
          acc[i][j] = __builtin_amdgcn_mfma_f32_16x16x32_bf16(af[i], bfr[j], acc[i][j], 0, 0, 0);
    }
    __syncthreads();
  }
  const int crow = (lane >> 4) * 4, ccol = lane & 15;
#pragma unroll
  for (int i = 0; i < 4; ++i)
#pragma unroll
    for (int j = 0; j < 4; ++j) {
      int gr = m0 + wm + i * 16 + crow;
      int gc = n0 + wn + j * 16 + ccol;
      float b = bias[gc];
#pragma unroll
      for (int rg = 0; rg < 4; ++rg) {
        float v = acc[i][j][rg] + b;
        v = 0.5f * v * (1.0f + erff(v * 0.70710678118654752f));
        H[(size_t)(gr + rg) * HID2 + gc] = bf16r(v);
      }
    }
}

// GEMM2: out[tok[pos]] (=/+=) gate * (H[pos] @ W2e + b2e); scatter epilogue.
__global__ __launch_bounds__(256, 2) void gemm2_k(
    const u16* __restrict__ A, const u16* __restrict__ Bt,
    const float* __restrict__ bias, const float* __restrict__ gate,
    const u32* __restrict__ perm, const int* __restrict__ cntpad,
    float* __restrict__ out, int expert) {
  const int m0 = blockIdx.y * BM;
  if (m0 >= *cntpad) return;
  __shared__ __align__(16) u16 As[BM * BK];
  __shared__ __align__(16) u16 Bs[BN * BK];
  const int K = HID2;
  const int tid = threadIdx.x;
  const int n0 = blockIdx.x * BN;
  const int wave = tid >> 6, lane = tid & 63;
  const int wm = (wave >> 1) * 64, wn = (wave & 1) * 64;
  const int lrow = lane & 15, lko = (lane >> 4) * 8;
  const int srow = tid >> 3, scol = (tid & 7) * 8;
  const int sw = (lrow & 7) * 8;
  f32x4 acc[4][4] = {};

  int ssc[4];
#pragma unroll
  for (int p = 0; p < 4; ++p) {
    int r = p * 32 + srow;
    ssc[p] = scol ^ ((r & 7) * 8);
  }

  for (int kt = 0; kt < K; kt += BK) {
#pragma unroll
    for (int p = 0; p < 4; ++p) {
      int r = p * 32 + srow;
      GLDS16(A + (size_t)(m0 + r) * K + kt + ssc[p], As + r * BK + scol);
      GLDS16(Bt + (size_t)(n0 + r) * K + kt + ssc[p], Bs + r * BK + scol);
    }
    __syncthreads();
#pragma unroll
    for (int kk = 0; kk < BK; kk += 32) {
      const int cx = (kk + lko) ^ sw;
      bf16x8 af[4], bfr[4];
#pragma unroll
      for (int i = 0; i < 4; ++i)
        af[i] = *(const bf16x8*)&As[(wm + i * 16 + lrow) * BK + cx];
#pragma unroll
      for (int j = 0; j < 4; ++j)
        bfr[j] = *(const bf16x8*)&Bs[(wn + j * 16 + lrow) * BK + cx];
#pragma unroll
      for (int i = 0; i < 4; ++i)
#pragma unroll
        for (int j = 0; j < 4; ++j)
          acc[i][j] = __builtin_amdgcn_mfma_f32_16x16x32_bf16(af[i], bfr[j], acc[i][j], 0, 0, 0);
    }
    __syncthreads();
  }
  const int crow = (lane >> 4) * 4, ccol = lane & 15;
#pragma unroll
  for (int i = 0; i < 4; ++i) {
    u32 ent[4];
#pragma unroll
    for (int rg = 0; rg < 4; ++rg)
      ent[rg] = perm[m0 + wm + i * 16 + crow + rg];
#pragma unroll
    for (int j = 0; j < 4; ++j) {
      int gc = n0 + wn + j * 16 + ccol;
      float b = bias[gc];
#pragma unroll
      for (int rg = 0; rg < 4; ++rg) {
        u32 en = ent[rg];
        if (en & F_PAD) continue;
        int tok = en & 0xFFFFu;
        float g = gate[tok * 4 + expert];
        float v = g * (acc[i][j][rg] + b);
        size_t o = (size_t)tok * ODIM + gc;
        if (en & F_FIRST) out[o] = v; else out[o] += v;
      }
    }
  }
}

extern "C" void kernel_launch(void* const* d_in, const int* in_sizes, int n_in,
                              void* d_out, int out_size, void* d_ws, size_t ws_size,
                              hipStream_t stream) {
  const float* X  = (const float*)d_in[0];
  const float* rw = (const float*)d_in[1];
  const float* rb = (const float*)d_in[2];
  const float* w1 = (const float*)d_in[3];
  const float* b1 = (const float*)d_in[4];
  const float* w2 = (const float*)d_in[5];
  const float* b2 = (const float*)d_in[6];
  float* out = (float*)d_out;

  // workspace layout (bytes)
  const size_t OFF_XB   = 0;                       // 33,554,432
  const size_t OFF_W1T  = 33554432;                // 67,108,864
  const size_t OFF_W2T  = 100663296;               // 29,360,128
  const size_t OFF_H    = 130023424;               // 67,108,864
  const size_t OFF_G    = 197132288;               // 65,536
  const size_t OFF_PAIR = 197197824;               // 16,384
  const size_t OFF_PERM = 197214208;               // 65,536
  const size_t OFF_CNT  = 197279744;               // 64
  const size_t NEED     = 197279808;
  if (ws_size < NEED) return;

  char* ws = (char*)d_ws;
  u16*   Xb   = (u16*)(ws + OFF_XB);
  u16*   w1bT = (u16*)(ws + OFF_W1T);
  u16*   w2bT = (u16*)(ws + OFF_W2T);
  u16*   Hb   = (u16*)(ws + OFF_H);
  float* gate = (float*)(ws + OFF_G);
  u32*   pair = (u32*)(ws + OFF_PAIR);
  u32*   perm = (u32*)(ws + OFF_PERM);
  int*   cnt  = (int*)(ws + OFF_CNT);
  int*   cntpad = cnt + 8;

  convx_k<<<16384, 256, 0, stream>>>(X, Xb, 4194304);
  router_k<<<4096, 256, 0, stream>>>(X, rw, rb, gate, pair);
  zero_k<<<1, 64, 0, stream>>>(cnt);
  build_k<<<16, 256, 0, stream>>>(pair, cnt, perm);
  pad_k<<<4, 128, 0, stream>>>(cnt, cntpad, perm);

  for (int e = 0; e < 4; ++e) {
    convT_k<<<dim3(HID2 / 64, HIDDEN / 64), 256, 0, stream>>>(
        w1 + (size_t)e * HIDDEN * HID2, w1bT, HIDDEN, HID2);
    gemm1_k<<<dim3(HID2 / BN, CAP / BM), 256, 0, stream>>>(
        Xb, w1bT, b1 + (size_t)e * HID2, Hb, perm + e * CAP, &cntpad[e]);
    convT_k<<<dim3(ODIM / 64, HID2 / 64), 256, 0, stream>>>(
        w2 + (size_t)e * HID2 * ODIM, w2bT, HID2, ODIM);
    gemm2_k<<<dim3(ODIM / BN, CAP / BM), 256, 0, stream>>>(
        Hb, w2bT, b2 + (size_t)e * ODIM, gate, perm + e * CAP, &cntpad[e],
        out, e);
  }
}